// Round 1
// baseline (171.420 us; speedup 1.0000x reference)
//
#include <hip/hip_runtime.h>
#include <hip/hip_bf16.h>

#define FEAT 256
#define HEADS 8
#define HD 32
#define POSN 128
#define NEGN 128
#define HWN 16384
#define BN 8
#define NSLOT 512
#define S_TOT 256
#define LN_EPS 1e-5f
#define NBKT 4096
#define AFF_OFF (NSLOT*FEAT)   /* 131072 floats: new_slots first, then affinities */

// ---------------- K1: exact feat_idx sampling (argsort ranks) ----------------
// One block per slot. Bucket counting-sort by value bucket (floor(v*4096),
// monotone in v), then exact selection within bucket using the full
// (value desc, index asc) comparator == stable argsort of -v.
__global__ __launch_bounds__(256) void k_sample(const float* __restrict__ curio,
                                                const int* __restrict__ mme_p,
                                                int* __restrict__ fi)
{
    __shared__ uint32_t hist[NBKT];    // 16KB
    __shared__ uint16_t offs[NBKT];    // 8KB
    __shared__ uint16_t sidx[HWN];     // 32KB
    __shared__ uint32_t ssum[256];     // 1KB
    int slot = blockIdx.x, t = threadIdx.x;
    const float* cm = curio + (size_t)slot * HWN;

    for (int i = t; i < NBKT; i += 256) hist[i] = 0;
    __syncthreads();
    for (int i = t; i < HWN; i += 256) {
        float v = cm[i];
        int b = (int)(v * 4096.0f);
        b = b < 0 ? 0 : (b > NBKT-1 ? NBKT-1 : b);
        atomicAdd(&hist[b], 1u);
    }
    __syncthreads();
    // descending-order exclusive prefix: offs[b] = sum_{b'>b} hist[b']
    uint32_t lsum = 0;
    int base = t * 16;
    for (int j = 0; j < 16; j++) lsum += hist[NBKT-1 - (base + j)];
    ssum[t] = lsum; __syncthreads();
    for (int off = 1; off < 256; off <<= 1) {
        uint32_t v = (t >= off) ? ssum[t - off] : 0u;
        __syncthreads();
        ssum[t] += v;
        __syncthreads();
    }
    uint32_t run = ssum[t] - lsum;
    for (int j = 0; j < 16; j++) {
        int b = NBKT-1 - (base + j);
        offs[b] = (uint16_t)run;
        run += hist[b];
    }
    __syncthreads();
    for (int i = t; i < NBKT; i += 256) hist[i] = 0;
    __syncthreads();
    // scatter indices grouped by bucket (order within bucket irrelevant)
    for (int i = t; i < HWN; i += 256) {
        float v = cm[i];
        int b = (int)(v * 4096.0f);
        b = b < 0 ? 0 : (b > NBKT-1 ? NBKT-1 : b);
        uint32_t pos = (uint32_t)offs[b] + atomicAdd(&hist[b], 1u);
        sidx[pos] = (uint16_t)i;
    }
    __syncthreads();

    int mme = mme_p[0];
    int stride = (HWN - POSN - mme) / NEGN;          // 127 for mme=0
    int r = (t < POSN) ? t : (POSN + stride * (t - POSN));
    // smallest b with offs[b] <= r  (offs nonincreasing in b)
    int lo = 0, hi = NBKT - 1;
    while (lo < hi) { int mid = (lo + hi) >> 1; if ((int)offs[mid] <= r) hi = mid; else lo = mid + 1; }
    int bkt = lo;
    int start = (int)offs[bkt];
    int cnt   = (int)hist[bkt];
    int rr = r - start;
    int besti = sidx[start + (rr < cnt ? rr : 0)];
    for (int j = 0; j < cnt; j++) {
        int ij = sidx[start + j];
        float vj = cm[ij];
        int rank = 0;
        for (int j2 = 0; j2 < cnt; j2++) {
            int i2 = sidx[start + j2];
            float v2 = cm[i2];
            if (v2 > vj || (v2 == vj && i2 < ij)) rank++;   // strictly before
        }
        if (rank == rr) { besti = ij; break; }
    }
    fi[t * NSLOT + slot] = besti;   // fi[s][n]
}

// ---------------- K2: q then folded qkw[n,h,f] = sum_d q[n,hd]*kw[hd,f] -----
__global__ __launch_bounds__(256) void k_qkw(const float* __restrict__ slots,
                                             const float* __restrict__ ipw,
                                             const float* __restrict__ ipb,
                                             float* __restrict__ qkw,
                                             float* __restrict__ qkb)
{
    __shared__ float srow[FEAT];
    __shared__ float qrow[FEAT];
    int n = blockIdx.x, t = threadIdx.x;
    srow[t] = slots[n * FEAT + t];
    __syncthreads();
    const float* qwrow = ipw + (size_t)t * FEAT;
    float acc = 0.f;
#pragma unroll 8
    for (int f = 0; f < FEAT; f++) acc += srow[f] * qwrow[f];
    const float scaling = 0.17677669529663687f;     // 32^-0.5
    qrow[t] = (acc + ipb[t]) * scaling;
    __syncthreads();
    if (t < HEADS) {
        float s = 0.f;
        for (int d = 0; d < HD; d++) s += qrow[t*HD + d] * ipb[FEAT + t*HD + d];
        qkb[n * HEADS + t] = s;
    }
    const float* kw = ipw + FEAT * FEAT;
    for (int e = t; e < HEADS * FEAT; e += 256) {
        int h = e >> 8, f = e & 255;
        float s = 0.f;
#pragma unroll
        for (int d = 0; d < HD; d++) s += qrow[h*HD + d] * kw[(h*HD + d) * FEAT + f];
        qkw[(size_t)n * (HEADS*FEAT) + e] = s;
    }
}

// ---------------- K3: affinities[s,n,h] = x_{s,n} . qkw[n,h] + qkb ----------
__global__ __launch_bounds__(256) void k_aff(const float* __restrict__ features,
                                             const float* __restrict__ pos_enc,
                                             const int* __restrict__ batch_idx,
                                             const int* __restrict__ fi,
                                             const float* __restrict__ qkw,
                                             const float* __restrict__ qkb,
                                             float* __restrict__ aff_out)
{
    __shared__ __align__(16) float qkw_l[HEADS * 260];
    __shared__ __align__(16) float x_l[32 * 260];
    __shared__ float qkb_l[HEADS];
    __shared__ int   fi_l[S_TOT];
    __shared__ float aff_l[32 * HEADS];
    int n = blockIdx.x, t = threadIdx.x;

    for (int e = t; e < HEADS * FEAT; e += 256) {
        int h = e >> 8, f = e & 255;
        qkw_l[h*260 + f] = qkw[(size_t)n * (HEADS*FEAT) + e];
    }
    if (t < HEADS) qkb_l[t] = qkb[n * HEADS + t];
    fi_l[t] = fi[t * NSLOT + n];
    int b = batch_idx[n];
    __syncthreads();

    int sl = t & 31, h = t >> 5;
    for (int tile = 0; tile < 8; tile++) {
        for (int e = t; e < 32 * FEAT; e += 256) {
            int j = e >> 8, f = e & 255;
            int row = fi_l[tile*32 + j];
            size_t basep = ((size_t)row * BN + b) * FEAT;
            x_l[j*260 + f] = features[basep + f] + pos_enc[basep + f];
        }
        __syncthreads();
        const float4* xv = (const float4*)&x_l[sl * 260];
        const float4* qv = (const float4*)&qkw_l[h * 260];
        float acc = 0.f;
#pragma unroll
        for (int f4 = 0; f4 < 64; f4++) {
            float4 a = xv[f4], q = qv[f4];
            acc += a.x*q.x + a.y*q.y + a.z*q.z + a.w*q.w;
        }
        aff_l[sl * HEADS + h] = acc + qkb_l[h];
        __syncthreads();
        {
            int s = tile*32 + (t >> 3), hh = t & 7;
            aff_out[(size_t)s * (NSLOT*HEADS) + n*HEADS + hh] = aff_l[t];
        }
        __syncthreads();
    }
}

// ---------------- K5: softmax + weighted-feat + Vproj + Oproj + LN ----------
__global__ __launch_bounds__(256) void k_out(const float* __restrict__ features,
                                             const int* __restrict__ batch_idx,
                                             const int* __restrict__ fi,
                                             const float* __restrict__ slots,
                                             const float* __restrict__ ipw,
                                             const float* __restrict__ ipb,
                                             const float* __restrict__ out_w,
                                             const float* __restrict__ out_b,
                                             const float* __restrict__ ln_g,
                                             const float* __restrict__ ln_b,
                                             const float* __restrict__ aff,
                                             float* __restrict__ out)
{
    __shared__ float a_l[HEADS][POSN];                 // 4KB
    __shared__ __align__(16) float wf[HEADS * 260];    // 8.3KB
    __shared__ int   fiP[POSN];
    __shared__ __align__(16) float ao_l[FEAT];
    __shared__ float r1[4], r2[4];
    int n = blockIdx.x, t = threadIdx.x;

    if (t < POSN) fiP[t] = fi[t * NSLOT + n];
    for (int e = t; e < POSN * HEADS; e += 256) {
        int p = e >> 3, h = e & 7;
        a_l[h][p] = aff[(size_t)p * (NSLOT*HEADS) + n*HEADS + h];
    }
    __syncthreads();
    {   // softmax over p (32 lanes per head)
        int h = t >> 5, l = t & 31;
        float v0 = a_l[h][l], v1 = a_l[h][l+32], v2 = a_l[h][l+64], v3 = a_l[h][l+96];
        float m = fmaxf(fmaxf(v0, v1), fmaxf(v2, v3));
        for (int off = 16; off > 0; off >>= 1) m = fmaxf(m, __shfl_xor(m, off, 32));
        float e0 = expf(v0 - m), e1 = expf(v1 - m), e2 = expf(v2 - m), e3 = expf(v3 - m);
        float s = e0 + e1 + e2 + e3;
        for (int off = 16; off > 0; off >>= 1) s += __shfl_xor(s, off, 32);
        float inv = 1.0f / s;
        a_l[h][l] = e0*inv; a_l[h][l+32] = e1*inv; a_l[h][l+64] = e2*inv; a_l[h][l+96] = e3*inv;
    }
    __syncthreads();
    // weighted feature sum: wf[h][f] = sum_p attn[h][p]*feat[fi(p),b,f]
    float acc[8] = {0,0,0,0,0,0,0,0};
    int b = batch_idx[n];
    for (int p = 0; p < POSN; p++) {
        size_t basep = ((size_t)fiP[p] * BN + b) * FEAT;
        float x = features[basep + t];
#pragma unroll
        for (int h = 0; h < 8; h++) acc[h] += a_l[h][p] * x;
    }
#pragma unroll
    for (int h = 0; h < 8; h++) wf[h*260 + t] = acc[h];
    __syncthreads();
    // V-projection: ao[g] = vb[g] + sum_f vw[g,f] * wf[g>>5][f]
    float ao = ipb[2*FEAT + t];
    {
        const float* vwrow = ipw + (size_t)(2*FEAT + t) * FEAT;
        const float4* wfv = (const float4*)&wf[(t >> 5) * 260];
#pragma unroll 4
        for (int f4 = 0; f4 < 64; f4++) {
            float4 w = *(const float4*)&vwrow[f4 * 4];
            float4 y = wfv[f4];
            ao += w.x*y.x + w.y*y.y + w.z*y.z + w.w*y.w;
        }
    }
    ao_l[t] = ao;
    __syncthreads();
    // out-proj + residual
    float xg = out_b[t] + slots[n * FEAT + t];
    {
        const float* owrow = out_w + (size_t)t * FEAT;
        const float4* av = (const float4*)ao_l;
#pragma unroll 4
        for (int f4 = 0; f4 < 64; f4++) {
            float4 w = *(const float4*)&owrow[f4 * 4];
            float4 y = av[f4];
            xg += w.x*y.x + w.y*y.y + w.z*y.z + w.w*y.w;
        }
    }
    // LayerNorm over 256 (block reduce)
    float s1 = xg, s2 = xg * xg;
    for (int off = 32; off > 0; off >>= 1) {
        s1 += __shfl_xor(s1, off, 64);
        s2 += __shfl_xor(s2, off, 64);
    }
    if ((t & 63) == 0) { r1[t >> 6] = s1; r2[t >> 6] = s2; }
    __syncthreads();
    float sum1 = r1[0] + r1[1] + r1[2] + r1[3];
    float sum2 = r2[0] + r2[1] + r2[2] + r2[3];
    float mu  = sum1 * (1.0f / FEAT);
    float var = sum2 * (1.0f / FEAT) - mu * mu;
    float nrm = (xg - mu) * rsqrtf(var + LN_EPS);
    out[n * FEAT + t] = nrm * ln_g[t] + ln_b[t];
}

extern "C" void kernel_launch(void* const* d_in, const int* in_sizes, int n_in,
                              void* d_out, int out_size, void* d_ws, size_t ws_size,
                              hipStream_t stream)
{
    (void)in_sizes; (void)n_in; (void)out_size; (void)ws_size;
    const float* slots    = (const float*)d_in[0];
    const float* features = (const float*)d_in[1];
    const float* pos_enc  = (const float*)d_in[2];
    const float* curio    = (const float*)d_in[3];
    const int*   batch_idx= (const int*)d_in[4];
    const float* ipw      = (const float*)d_in[5];
    const float* ipb      = (const float*)d_in[6];
    const float* out_w    = (const float*)d_in[7];
    const float* out_b    = (const float*)d_in[8];
    const float* ln_g     = (const float*)d_in[9];
    const float* ln_b     = (const float*)d_in[10];
    const int*   mme      = (const int*)d_in[11];
    float* out = (float*)d_out;

    char* ws = (char*)d_ws;
    int*   fi  = (int*)ws;                                  // 256*512*4 = 512KB
    float* qkw = (float*)(ws + (512 << 10));                // 512*2048*4 = 4MB
    float* qkb = (float*)(ws + (512 << 10) + (4 << 20));    // 16KB
    float* aff = out + AFF_OFF;

    hipLaunchKernelGGL(k_sample, dim3(NSLOT), dim3(256), 0, stream, curio, mme, fi);
    hipLaunchKernelGGL(k_qkw,    dim3(NSLOT), dim3(256), 0, stream, slots, ipw, ipb, qkw, qkb);
    hipLaunchKernelGGL(k_aff,    dim3(NSLOT), dim3(256), 0, stream, features, pos_enc, batch_idx, fi, qkw, qkb, aff);
    hipLaunchKernelGGL(k_out,    dim3(NSLOT), dim3(256), 0, stream, features, batch_idx, fi, slots, ipw, ipb,
                       out_w, out_b, ln_g, ln_b, aff, out);
}

// Round 2
// 166.781 us; speedup vs baseline: 1.0278x; 1.0278x over previous
//
#include <hip/hip_runtime.h>
#include <hip/hip_bf16.h>

#define FEAT 256
#define HEADS 8
#define HD 32
#define POSN 128
#define NEGN 128
#define HWN 16384
#define BN 8
#define NSLOT 512
#define S_TOT 256
#define LN_EPS 1e-5f
#define NBKT 4096
#define AFF_OFF (NSLOT*FEAT)   /* 131072 floats: new_slots first, then affinities */

// ---------------- K1: exact feat_idx sampling (argsort ranks) ----------------
__global__ __launch_bounds__(256) void k_sample(const float* __restrict__ curio,
                                                const int* __restrict__ mme_p,
                                                int* __restrict__ fi)
{
    __shared__ uint32_t hist[NBKT];    // 16KB
    __shared__ uint16_t offs[NBKT];    // 8KB
    __shared__ uint16_t sidx[HWN];     // 32KB
    __shared__ uint32_t ssum[256];     // 1KB
    int slot = blockIdx.x, t = threadIdx.x;
    const float* cm = curio + (size_t)slot * HWN;

    for (int i = t; i < NBKT; i += 256) hist[i] = 0;
    __syncthreads();
    for (int i = t; i < HWN; i += 256) {
        float v = cm[i];
        int b = (int)(v * 4096.0f);
        b = b < 0 ? 0 : (b > NBKT-1 ? NBKT-1 : b);
        atomicAdd(&hist[b], 1u);
    }
    __syncthreads();
    uint32_t lsum = 0;
    int base = t * 16;
    for (int j = 0; j < 16; j++) lsum += hist[NBKT-1 - (base + j)];
    ssum[t] = lsum; __syncthreads();
    for (int off = 1; off < 256; off <<= 1) {
        uint32_t v = (t >= off) ? ssum[t - off] : 0u;
        __syncthreads();
        ssum[t] += v;
        __syncthreads();
    }
    uint32_t run = ssum[t] - lsum;
    for (int j = 0; j < 16; j++) {
        int b = NBKT-1 - (base + j);
        offs[b] = (uint16_t)run;
        run += hist[b];
    }
    __syncthreads();
    for (int i = t; i < NBKT; i += 256) hist[i] = 0;
    __syncthreads();
    for (int i = t; i < HWN; i += 256) {
        float v = cm[i];
        int b = (int)(v * 4096.0f);
        b = b < 0 ? 0 : (b > NBKT-1 ? NBKT-1 : b);
        uint32_t pos = (uint32_t)offs[b] + atomicAdd(&hist[b], 1u);
        sidx[pos] = (uint16_t)i;
    }
    __syncthreads();

    int mme = mme_p[0];
    int stride = (HWN - POSN - mme) / NEGN;          // 127 for mme=0
    int r = (t < POSN) ? t : (POSN + stride * (t - POSN));
    int lo = 0, hi = NBKT - 1;
    while (lo < hi) { int mid = (lo + hi) >> 1; if ((int)offs[mid] <= r) hi = mid; else lo = mid + 1; }
    int bkt = lo;
    int start = (int)offs[bkt];
    int cnt   = (int)hist[bkt];
    int rr = r - start;
    int besti = sidx[start + (rr < cnt ? rr : 0)];
    for (int j = 0; j < cnt; j++) {
        int ij = sidx[start + j];
        float vj = cm[ij];
        int rank = 0;
        for (int j2 = 0; j2 < cnt; j2++) {
            int i2 = sidx[start + j2];
            float v2 = cm[i2];
            if (v2 > vj || (v2 == vj && i2 < ij)) rank++;
        }
        if (rank == rr) { besti = ij; break; }
    }
    fi[t * NSLOT + slot] = besti;   // fi[s][n]
}

// ---------------- K2: q then folded qkw[n,h,f] = sum_d q[n,hd]*kw[hd,f] -----
__global__ __launch_bounds__(256) void k_qkw(const float* __restrict__ slots,
                                             const float* __restrict__ ipw,
                                             const float* __restrict__ ipb,
                                             float* __restrict__ qkw,
                                             float* __restrict__ qkb)
{
    __shared__ float srow[FEAT];
    __shared__ float qrow[FEAT];
    int n = blockIdx.x, t = threadIdx.x;
    srow[t] = slots[n * FEAT + t];
    __syncthreads();
    const float* qwrow = ipw + (size_t)t * FEAT;
    float acc = 0.f;
#pragma unroll 8
    for (int f = 0; f < FEAT; f++) acc += srow[f] * qwrow[f];
    const float scaling = 0.17677669529663687f;     // 32^-0.5
    qrow[t] = (acc + ipb[t]) * scaling;
    __syncthreads();
    if (t < HEADS) {
        float s = 0.f;
        for (int d = 0; d < HD; d++) s += qrow[t*HD + d] * ipb[FEAT + t*HD + d];
        qkb[n * HEADS + t] = s;
    }
    const float* kw = ipw + FEAT * FEAT;
    for (int e = t; e < HEADS * FEAT; e += 256) {
        int h = e >> 8, f = e & 255;
        float s = 0.f;
#pragma unroll
        for (int d = 0; d < HD; d++) s += qrow[h*HD + d] * kw[(h*HD + d) * FEAT + f];
        qkw[(size_t)n * (HEADS*FEAT) + e] = s;
    }
}

// ---------------- K3 v2: register-resident affinity ------------------------
// grid (4, NSLOT): blockIdx.x = quarter (64 rows), blockIdx.y = slot.
// Lane l holds x[4l..4l+3] (two float4 gathers, no LDS staging) and
// qkw[h][4l..4l+3] for all 8 heads in 32 VGPRs. 8 partials reduced across
// 64 lanes via value-halving butterfly (7 shuffles); head h lands in lane h.
__global__ __launch_bounds__(256) void k_aff(const float* __restrict__ features,
                                             const float* __restrict__ pos_enc,
                                             const int* __restrict__ batch_idx,
                                             const int* __restrict__ fi,
                                             const float* __restrict__ qkw,
                                             const float* __restrict__ qkb,
                                             float* __restrict__ aff_out)
{
    __shared__ int   fi_l[64];
    __shared__ float qkb_l[HEADS];
    int n = blockIdx.y, q = blockIdx.x;
    int t = threadIdx.x, lane = t & 63, w = t >> 6;

    if (t < 64) fi_l[t] = fi[(q * 64 + t) * NSLOT + n];
    if (t < HEADS) qkb_l[t] = qkb[n * HEADS + t];
    int b = batch_idx[n];

    const float* qk = qkw + (size_t)n * (HEADS*FEAT) + 4 * lane;
    float4 qw0 = *(const float4*)(qk + 0*FEAT);
    float4 qw1 = *(const float4*)(qk + 1*FEAT);
    float4 qw2 = *(const float4*)(qk + 2*FEAT);
    float4 qw3 = *(const float4*)(qk + 3*FEAT);
    float4 qw4 = *(const float4*)(qk + 4*FEAT);
    float4 qw5 = *(const float4*)(qk + 5*FEAT);
    float4 qw6 = *(const float4*)(qk + 6*FEAT);
    float4 qw7 = *(const float4*)(qk + 7*FEAT);
    __syncthreads();
    float qb = qkb_l[lane & 7];

    int b0 = lane & 1, b1 = (lane >> 1) & 1, b2 = (lane >> 2) & 1;

    int r0 = w * 16;
    size_t base = ((size_t)fi_l[r0] * BN + b) * FEAT + 4 * lane;
    float4 f4 = *(const float4*)(features + base);
    float4 g4 = *(const float4*)(pos_enc + base);

    for (int i = 0; i < 16; i++) {
        float4 cf = f4, cg = g4;
        if (i < 15) {
            size_t nb = ((size_t)fi_l[r0 + i + 1] * BN + b) * FEAT + 4 * lane;
            f4 = *(const float4*)(features + nb);
            g4 = *(const float4*)(pos_enc + nb);
        }
        float x0 = cf.x + cg.x, x1 = cf.y + cg.y, x2 = cf.z + cg.z, x3 = cf.w + cg.w;
        float p0 = x0*qw0.x + x1*qw0.y + x2*qw0.z + x3*qw0.w;
        float p1 = x0*qw1.x + x1*qw1.y + x2*qw1.z + x3*qw1.w;
        float p2 = x0*qw2.x + x1*qw2.y + x2*qw2.z + x3*qw2.w;
        float p3 = x0*qw3.x + x1*qw3.y + x2*qw3.z + x3*qw3.w;
        float p4 = x0*qw4.x + x1*qw4.y + x2*qw4.z + x3*qw4.w;
        float p5 = x0*qw5.x + x1*qw5.y + x2*qw5.z + x3*qw5.w;
        float p6 = x0*qw6.x + x1*qw6.y + x2*qw6.z + x3*qw6.w;
        float p7 = x0*qw7.x + x1*qw7.y + x2*qw7.z + x3*qw7.w;
        // step 1 (mask 1, head bit0): a_j holds head 2j+b0
        float s0 = b0 ? p0 : p1, s1 = b0 ? p2 : p3, s2 = b0 ? p4 : p5, s3 = b0 ? p6 : p7;
        float a0 = (b0 ? p1 : p0) + __shfl_xor(s0, 1);
        float a1 = (b0 ? p3 : p2) + __shfl_xor(s1, 1);
        float a2 = (b0 ? p5 : p4) + __shfl_xor(s2, 1);
        float a3 = (b0 ? p7 : p6) + __shfl_xor(s3, 1);
        // step 2 (mask 2, head bit1): c_m holds head 4m+2b1+b0
        float u0 = b1 ? a0 : a1, u1 = b1 ? a2 : a3;
        float c0 = (b1 ? a1 : a0) + __shfl_xor(u0, 2);
        float c1 = (b1 ? a3 : a2) + __shfl_xor(u1, 2);
        // step 3 (mask 4, head bit2): d holds head lane&7
        float u2 = b2 ? c0 : c1;
        float d = (b2 ? c1 : c0) + __shfl_xor(u2, 4);
        d += __shfl_xor(d, 8);
        d += __shfl_xor(d, 16);
        d += __shfl_xor(d, 32);
        d += qb;
        if (lane < 8) {
            int s = q * 64 + r0 + i;
            aff_out[(size_t)s * (NSLOT*HEADS) + n*HEADS + lane] = d;
        }
    }
}

// ---------------- K5: softmax + weighted-feat + Vproj + Oproj + LN ----------
__global__ __launch_bounds__(256) void k_out(const float* __restrict__ features,
                                             const int* __restrict__ batch_idx,
                                             const int* __restrict__ fi,
                                             const float* __restrict__ slots,
                                             const float* __restrict__ ipw,
                                             const float* __restrict__ ipb,
                                             const float* __restrict__ out_w,
                                             const float* __restrict__ out_b,
                                             const float* __restrict__ ln_g,
                                             const float* __restrict__ ln_b,
                                             const float* __restrict__ aff,
                                             float* __restrict__ out)
{
    __shared__ float a_l[HEADS][POSN];                   // 4KB
    __shared__ __align__(16) float attnT[POSN][8];       // 4KB  (attn transposed)
    __shared__ float4 wfp4[4][HEADS][64];                // 32KB per-wave partials
    __shared__ float4 wf4[HEADS][64];                    // 8KB  combined wf
    __shared__ int   fiP[POSN];
    __shared__ __align__(16) float ao_l[FEAT];
    __shared__ float r1[4], r2[4];
    int n = blockIdx.x, t = threadIdx.x;

    if (t < POSN) fiP[t] = fi[t * NSLOT + n];
    for (int e = t; e < POSN * HEADS; e += 256) {
        int p = e >> 3, h = e & 7;
        a_l[h][p] = aff[(size_t)p * (NSLOT*HEADS) + n*HEADS + h];
    }
    __syncthreads();
    {   // softmax over p (32 lanes per head)
        int h = t >> 5, l = t & 31;
        float v0 = a_l[h][l], v1 = a_l[h][l+32], v2 = a_l[h][l+64], v3 = a_l[h][l+96];
        float m = fmaxf(fmaxf(v0, v1), fmaxf(v2, v3));
        for (int off = 16; off > 0; off >>= 1) m = fmaxf(m, __shfl_xor(m, off, 32));
        float e0 = expf(v0 - m), e1 = expf(v1 - m), e2 = expf(v2 - m), e3 = expf(v3 - m);
        float s = e0 + e1 + e2 + e3;
        for (int off = 16; off > 0; off >>= 1) s += __shfl_xor(s, off, 32);
        float inv = 1.0f / s;
        attnT[l   ][h] = e0*inv;
        attnT[l+32][h] = e1*inv;
        attnT[l+64][h] = e2*inv;
        attnT[l+96][h] = e3*inv;
    }
    __syncthreads();
    // weighted feature sum: wave g handles p in [g*32, g*32+32); lane q = f-quad
    int g = t >> 6, qd = t & 63;
    int b = batch_idx[n];
    float4 ac0 = {0,0,0,0}, ac1 = {0,0,0,0}, ac2 = {0,0,0,0}, ac3 = {0,0,0,0};
    float4 ac4 = {0,0,0,0}, ac5 = {0,0,0,0}, ac6 = {0,0,0,0}, ac7 = {0,0,0,0};
    for (int i = 0; i < 32; i++) {
        int p = g * 32 + i;
        size_t basep = ((size_t)fiP[p] * BN + b) * FEAT;
        float4 x = *((const float4*)(features + basep) + qd);
        float4 w03 = *(const float4*)&attnT[p][0];
        float4 w47 = *(const float4*)&attnT[p][4];
        ac0.x += w03.x*x.x; ac0.y += w03.x*x.y; ac0.z += w03.x*x.z; ac0.w += w03.x*x.w;
        ac1.x += w03.y*x.x; ac1.y += w03.y*x.y; ac1.z += w03.y*x.z; ac1.w += w03.y*x.w;
        ac2.x += w03.z*x.x; ac2.y += w03.z*x.y; ac2.z += w03.z*x.z; ac2.w += w03.z*x.w;
        ac3.x += w03.w*x.x; ac3.y += w03.w*x.y; ac3.z += w03.w*x.z; ac3.w += w03.w*x.w;
        ac4.x += w47.x*x.x; ac4.y += w47.x*x.y; ac4.z += w47.x*x.z; ac4.w += w47.x*x.w;
        ac5.x += w47.y*x.x; ac5.y += w47.y*x.y; ac5.z += w47.y*x.z; ac5.w += w47.y*x.w;
        ac6.x += w47.z*x.x; ac6.y += w47.z*x.y; ac6.z += w47.z*x.z; ac6.w += w47.z*x.w;
        ac7.x += w47.w*x.x; ac7.y += w47.w*x.y; ac7.z += w47.w*x.z; ac7.w += w47.w*x.w;
    }
    wfp4[g][0][qd] = ac0; wfp4[g][1][qd] = ac1; wfp4[g][2][qd] = ac2; wfp4[g][3][qd] = ac3;
    wfp4[g][4][qd] = ac4; wfp4[g][5][qd] = ac5; wfp4[g][6][qd] = ac6; wfp4[g][7][qd] = ac7;
    __syncthreads();
    for (int e = t; e < HEADS * 64; e += 256) {
        int h = e >> 6, q2 = e & 63;
        float4 s0 = wfp4[0][h][q2], s1 = wfp4[1][h][q2], s2 = wfp4[2][h][q2], s3 = wfp4[3][h][q2];
        float4 s; s.x = s0.x+s1.x+s2.x+s3.x; s.y = s0.y+s1.y+s2.y+s3.y;
        s.z = s0.z+s1.z+s2.z+s3.z; s.w = s0.w+s1.w+s2.w+s3.w;
        wf4[h][q2] = s;
    }
    __syncthreads();
    // V-projection: ao[g] = vb[g] + sum_f vw[g,f] * wf[g>>5][f]
    float ao = ipb[2*FEAT + t];
    {
        const float* vwrow = ipw + (size_t)(2*FEAT + t) * FEAT;
        const float4* wfv = (const float4*)&wf4[t >> 5][0];
#pragma unroll 4
        for (int f4 = 0; f4 < 64; f4++) {
            float4 w = *(const float4*)&vwrow[f4 * 4];
            float4 y = wfv[f4];
            ao += w.x*y.x + w.y*y.y + w.z*y.z + w.w*y.w;
        }
    }
    ao_l[t] = ao;
    __syncthreads();
    // out-proj + residual
    float xg = out_b[t] + slots[n * FEAT + t];
    {
        const float* owrow = out_w + (size_t)t * FEAT;
        const float4* av = (const float4*)ao_l;
#pragma unroll 4
        for (int f4 = 0; f4 < 64; f4++) {
            float4 w = *(const float4*)&owrow[f4 * 4];
            float4 y = av[f4];
            xg += w.x*y.x + w.y*y.y + w.z*y.z + w.w*y.w;
        }
    }
    // LayerNorm over 256 (block reduce)
    float s1 = xg, s2 = xg * xg;
    for (int off = 32; off > 0; off >>= 1) {
        s1 += __shfl_xor(s1, off, 64);
        s2 += __shfl_xor(s2, off, 64);
    }
    if ((t & 63) == 0) { r1[t >> 6] = s1; r2[t >> 6] = s2; }
    __syncthreads();
    float sum1 = r1[0] + r1[1] + r1[2] + r1[3];
    float sum2 = r2[0] + r2[1] + r2[2] + r2[3];
    float mu  = sum1 * (1.0f / FEAT);
    float var = sum2 * (1.0f / FEAT) - mu * mu;
    float nrm = (xg - mu) * rsqrtf(var + LN_EPS);
    out[n * FEAT + t] = nrm * ln_g[t] + ln_b[t];
}

extern "C" void kernel_launch(void* const* d_in, const int* in_sizes, int n_in,
                              void* d_out, int out_size, void* d_ws, size_t ws_size,
                              hipStream_t stream)
{
    (void)in_sizes; (void)n_in; (void)out_size; (void)ws_size;
    const float* slots    = (const float*)d_in[0];
    const float* features = (const float*)d_in[1];
    const float* pos_enc  = (const float*)d_in[2];
    const float* curio    = (const float*)d_in[3];
    const int*   batch_idx= (const int*)d_in[4];
    const float* ipw      = (const float*)d_in[5];
    const float* ipb      = (const float*)d_in[6];
    const float* out_w    = (const float*)d_in[7];
    const float* out_b    = (const float*)d_in[8];
    const float* ln_g     = (const float*)d_in[9];
    const float* ln_b     = (const float*)d_in[10];
    const int*   mme      = (const int*)d_in[11];
    float* out = (float*)d_out;

    char* ws = (char*)d_ws;
    int*   fi  = (int*)ws;                                  // 256*512*4 = 512KB
    float* qkw = (float*)(ws + (512 << 10));                // 512*2048*4 = 4MB
    float* qkb = (float*)(ws + (512 << 10) + (4 << 20));    // 16KB
    float* aff = out + AFF_OFF;

    hipLaunchKernelGGL(k_sample, dim3(NSLOT), dim3(256), 0, stream, curio, mme, fi);
    hipLaunchKernelGGL(k_qkw,    dim3(NSLOT), dim3(256), 0, stream, slots, ipw, ipb, qkw, qkb);
    hipLaunchKernelGGL(k_aff,    dim3(4, NSLOT), dim3(256), 0, stream, features, pos_enc, batch_idx, fi, qkw, qkb, aff);
    hipLaunchKernelGGL(k_out,    dim3(NSLOT), dim3(256), 0, stream, features, batch_idx, fi, slots, ipw, ipb,
                       out_w, out_b, ln_g, ln_b, aff, out);
}